// Round 5
// baseline (633.942 us; speedup 1.0000x reference)
//
#include <hip/hip_runtime.h>
#include <hip/hip_bf16.h>
#include <cstddef>

// X=4096, H=1024, L=8, VT=512, ET=1024
// z = [input_x(4096) ; h_prev[l](1024) ; prev_layer(1024)] -> 6144 cols
// Wg: (L, 4H, 6144) row-major fp32. Gate order: i, f, o, s.

#define XDIM 4096
#define HDIM 1024
#define LNUM 8
#define ZDIM 6144
#define ZPAR 5120   // X + H (scan-independent prefix)
#define VT 512
#define ET 1024
#define NCNT 16              // split completion counters (contention /16)
#define GRP (1024 / NCNT)    // blocks per counter = 64

__device__ __forceinline__ float sigmoidf_(float v) {
    return 1.0f / (1.0f + expf(-v));
}

// ---------------------------------------------------------------------------
// Kernel P: prefix dots for ALL rows (5120 cols) + fused layer-0 LSTM cell.
// grid = 4096 blocks (8 layers x 512) x 256. Block b: l=b>>9, h0=(b&511)*2.
// Wave w computes rows rA=l*4096+w*1024+h0 and rB=rA+1 (shared LDS z reads).
// Block 0 additionally zeroes the carry-chain counters (visible to the next
// kernel via the stream-order kernel boundary).
// ---------------------------------------------------------------------------
__global__ __launch_bounds__(256, 4) void prefix_kernel(
    const float* __restrict__ x,
    const float* __restrict__ hprev,
    const float* __restrict__ Wg,
    const float* __restrict__ bg,
    const float* __restrict__ old_state,
    float* __restrict__ partial,
    float* __restrict__ hidden,
    int* __restrict__ cnt)
{
    __shared__ float z[ZPAR];      // 20 KB
    __shared__ float g2[4][2];

    const int tid  = threadIdx.x;
    const int wave = tid >> 6;
    const int lane = tid & 63;
    const int l    = blockIdx.x >> 9;
    const int h0   = (blockIdx.x & 511) * 2;

    if (blockIdx.x == 0 && tid < LNUM * NCNT)
        cnt[tid] = 0;

    // stage z = [x ; h_prev[l]]
    for (int i = tid; i < XDIM / 4; i += 256)
        reinterpret_cast<float4*>(z)[i] = reinterpret_cast<const float4*>(x)[i];
    reinterpret_cast<float4*>(z + XDIM)[tid] =
        reinterpret_cast<const float4*>(hprev + (size_t)l * HDIM)[tid];
    __syncthreads();

    const size_t rA = (size_t)l * 4096 + (size_t)wave * HDIM + h0;
    const size_t rB = rA + 1;
    const float4* __restrict__ WA = reinterpret_cast<const float4*>(Wg + rA * ZDIM);
    const float4* __restrict__ WB = reinterpret_cast<const float4*>(Wg + rB * ZDIM);
    const float4* __restrict__ z4 = reinterpret_cast<const float4*>(z);

    float accA = 0.0f, accB = 0.0f;
    #pragma unroll 4
    for (int p = 0; p < 20; ++p) {              // 1280 float4 / 64 lanes
        const int idx = p * 64 + lane;
        float4 wa = WA[idx];
        float4 wb = WB[idx];
        float4 v  = z4[idx];
        accA += wa.x * v.x + wa.y * v.y + wa.z * v.z + wa.w * v.w;
        accB += wb.x * v.x + wb.y * v.y + wb.z * v.z + wb.w * v.w;
    }
    #pragma unroll
    for (int off = 32; off > 0; off >>= 1) {
        accA += __shfl_down(accA, off, 64);
        accB += __shfl_down(accB, off, 64);
    }

    if (l > 0) {
        if (lane == 0) {
            partial[rA] = accA + bg[rA];
            partial[rB] = accB + bg[rB];
        }
    } else {
        if (lane == 0) {
            g2[wave][0] = accA + bg[rA];
            g2[wave][1] = accB + bg[rB];
        }
        __syncthreads();
        if (tid == 0) {
            #pragma unroll
            for (int k = 0; k < 2; ++k) {
                const float ig = sigmoidf_(g2[0][k]);
                const float fg = sigmoidf_(g2[1][k]);
                const float og = sigmoidf_(g2[2][k]);
                const float sg = tanhf(g2[3][k]);
                const float ns = fg * old_state[h0 + k] + ig * sg;
                hidden[h0 + k] = og * tanhf(ns);
            }
        }
    }
}

// ---------------------------------------------------------------------------
// Kernel C: persistent carry chain, layers 1..7 in ONE launch.
// 1024 blocks x 256 (block = h, wave = gate). __launch_bounds__(256,4) caps
// VGPR at 128 -> 4 blocks/CU x 256 CUs = all 1024 blocks co-resident
// (LDS 4KB is not limiting) -> flag sync cannot deadlock.
// Per layer: W carry segment (4 float4/lane) + partial are PREFETCHED into
// registers before the spin-wait, so HBM latency hides under the sync.
// Signal = release-scope atomicAdd into 16 split counters (64-deep chains);
// wait = 16 lanes polling one counter each with acquire loads.
// ---------------------------------------------------------------------------
__global__ __launch_bounds__(256, 4) void carry_chain_kernel(
    const float* __restrict__ Wg,
    const float* __restrict__ partial,
    const float* __restrict__ old_state,
    float* __restrict__ hidden,
    int* __restrict__ cnt)
{
    __shared__ float hp[HDIM];   // 4 KB
    __shared__ float gred[4];

    const int tid  = threadIdx.x;
    const int wave = tid >> 6;
    const int lane = tid & 63;
    const int h    = blockIdx.x;

    // prefetch layer-1 carry weights + partial (hidden[0] ready: prior kernel)
    size_t row = (size_t)4096 + (size_t)wave * HDIM + h;
    {
        const float4* __restrict__ W4 =
            reinterpret_cast<const float4*>(Wg + row * ZDIM + ZPAR);
        // issued immediately; consumed after the (free) l=1 "wait"
        asm volatile("" ::: "memory");
    }
    const float4* __restrict__ W4 =
        reinterpret_cast<const float4*>(Wg + row * ZDIM + ZPAR);
    float4 w0 = W4[lane], w1 = W4[64 + lane], w2 = W4[128 + lane], w3 = W4[192 + lane];
    float part = partial[row];

    for (int l = 1; l < LNUM; ++l) {
        if (l > 1) {
            if (tid < NCNT) {
                while (__hip_atomic_load(&cnt[(l - 1) * NCNT + tid],
                                         __ATOMIC_ACQUIRE,
                                         __HIP_MEMORY_SCOPE_AGENT) < GRP)
                    __builtin_amdgcn_s_sleep(2);
            }
        }
        __syncthreads();   // join waiters; also protects hp/gred reuse

        // stage hidden[l-1] (256 thr x float4 = 1024 floats)
        reinterpret_cast<float4*>(hp)[tid] =
            reinterpret_cast<const float4*>(hidden + (size_t)(l - 1) * HDIM)[tid];
        __syncthreads();

        const float4* __restrict__ h4 = reinterpret_cast<const float4*>(hp);
        float4 v0 = h4[lane], v1 = h4[64 + lane], v2 = h4[128 + lane], v3 = h4[192 + lane];
        float acc = w0.x * v0.x + w0.y * v0.y + w0.z * v0.z + w0.w * v0.w
                  + w1.x * v1.x + w1.y * v1.y + w1.z * v1.z + w1.w * v1.w
                  + w2.x * v2.x + w2.y * v2.y + w2.z * v2.z + w2.w * v2.w
                  + w3.x * v3.x + w3.y * v3.y + w3.z * v3.z + w3.w * v3.w;

        // prefetch next layer's W + partial while this layer finishes
        float part_next = 0.0f;
        if (l + 1 < LNUM) {
            row += 4096;
            const float4* __restrict__ NW4 =
                reinterpret_cast<const float4*>(Wg + row * ZDIM + ZPAR);
            w0 = NW4[lane]; w1 = NW4[64 + lane]; w2 = NW4[128 + lane]; w3 = NW4[192 + lane];
            part_next = partial[row];
        }

        #pragma unroll
        for (int off = 32; off > 0; off >>= 1)
            acc += __shfl_down(acc, off, 64);
        if (lane == 0)
            gred[wave] = acc + part;            // partial already includes bg
        __syncthreads();

        if (tid == 0) {
            const float ig = sigmoidf_(gred[0]);
            const float fg = sigmoidf_(gred[1]);
            const float og = sigmoidf_(gred[2]);
            const float sg = tanhf(gred[3]);
            const float ns = fg * old_state[(size_t)l * HDIM + h] + ig * sg;
            hidden[(size_t)l * HDIM + h] = og * tanhf(ns);
            // release: orders the hidden store before the counter increment
            __hip_atomic_fetch_add(&cnt[l * NCNT + (h & (NCNT - 1))], 1,
                                   __ATOMIC_RELEASE, __HIP_MEMORY_SCOPE_AGENT);
        }
        part = part_next;
    }
}

// ---------------------------------------------------------------------------
// Kernel H: heads. One block per output row (1536 blocks x 256).
// flat (32 KB) is L2-hot broadcast -> no LDS staging.
// ---------------------------------------------------------------------------
__global__ __launch_bounds__(256) void head_kernel(
    const float* __restrict__ Wy, const float* __restrict__ by,
    const float* __restrict__ We, const float* __restrict__ be,
    const float* __restrict__ flat,
    float* __restrict__ out)
{
    __shared__ float gred[4];

    const int tid  = threadIdx.x;
    const int wave = tid >> 6;
    const int lane = tid & 63;
    const int r    = blockIdx.x;

    const float* __restrict__ W;
    float b;
    if (r < VT) { W = Wy + (size_t)r * (LNUM * HDIM);        b = by[r]; }
    else        { W = We + (size_t)(r - VT) * (LNUM * HDIM); b = be[r - VT]; }

    const float4* __restrict__ W4 = reinterpret_cast<const float4*>(W);
    const float4* __restrict__ f4 = reinterpret_cast<const float4*>(flat);

    float acc = 0.0f;
    #pragma unroll
    for (int j = 0; j < 8; ++j) {               // 2048 float4 / 4 waves / 64 lanes
        const int idx = wave * 512 + j * 64 + lane;
        float4 w = W4[idx];
        float4 v = f4[idx];
        acc += w.x * v.x + w.y * v.y + w.z * v.z + w.w * v.w;
    }
    #pragma unroll
    for (int off = 32; off > 0; off >>= 1)
        acc += __shfl_down(acc, off, 64);
    if (lane == 0) gred[wave] = acc;
    __syncthreads();

    if (tid == 0)
        out[r] = gred[0] + gred[1] + gred[2] + gred[3] + b;
}

// ---------------------------------------------------------------------------
extern "C" void kernel_launch(void* const* d_in, const int* in_sizes, int n_in,
                              void* d_out, int out_size, void* d_ws, size_t ws_size,
                              hipStream_t stream)
{
    const float* x         = (const float*)d_in[0];
    const float* hprev     = (const float*)d_in[1];
    const float* Wg        = (const float*)d_in[2];
    const float* bg        = (const float*)d_in[3];
    const float* old_state = (const float*)d_in[4];
    const float* Wy        = (const float*)d_in[5];
    const float* by        = (const float*)d_in[6];
    const float* We        = (const float*)d_in[7];
    const float* be        = (const float*)d_in[8];
    float* out = (float*)d_out;

    float* hidden  = (float*)d_ws;                       // L*H floats
    float* partial = hidden + LNUM * HDIM;               // L*4H floats
    int*   cnt     = (int*)(partial + LNUM * 4 * HDIM);  // L*NCNT ints

    // 1) prefix dots (all layers) + layer-0 cell + counter zeroing
    prefix_kernel<<<4096, 256, 0, stream>>>(
        x, hprev, Wg, bg, old_state, partial, hidden, cnt);

    // 2) persistent carry chain, layers 1..7 (one launch, flag sync)
    carry_chain_kernel<<<1024, 256, 0, stream>>>(
        Wg, partial, old_state, hidden, cnt);

    // 3) heads
    head_kernel<<<VT + ET, 256, 0, stream>>>(Wy, by, We, be, hidden, out);
}

// Round 6
// 172.272 us; speedup vs baseline: 3.6799x; 3.6799x over previous
//
#include <hip/hip_runtime.h>
#include <hip/hip_bf16.h>
#include <cstddef>

// X=4096, H=1024, L=8, VT=512, ET=1024
// z = [input_x(4096) ; h_prev[l](1024) ; prev_layer(1024)] -> 6144 cols
// Wg: (L, 4H, 6144) row-major fp32. Gate order: i, f, o, s.

#define XDIM 4096
#define HDIM 1024
#define LNUM 8
#define ZDIM 6144
#define ZPAR 5120   // X + H (scan-independent prefix)
#define VT 512
#define ET 1024

__device__ __forceinline__ float sigmoidf_(float v) {
    return 1.0f / (1.0f + expf(-v));
}

// ---------------------------------------------------------------------------
// Layer kernel (l >= 1): full 6144-col GEMV for layer l + LSTM cell.
// grid = 1024 blocks x 256. Block b owns h=b; wave q computes gate row
// l*4096 + q*1024 + h over all 6144 cols (z staged in 24 KB LDS:
// [x ; hprev_l ; hidden_{l-1}]). Cell math inline -> hidden[l][h].
// Two interleaved W streams per wave (split halves) for load ILP.
// 4 blocks/CU resident (VGPR<=128, LDS 24KB) -> whole grid resident.
// ---------------------------------------------------------------------------
__global__ __launch_bounds__(256, 4) void layer_kernel(
    const float* __restrict__ x,
    const float* __restrict__ hprev,
    const float* __restrict__ Wg,
    const float* __restrict__ bg,
    const float* __restrict__ old_state,
    const float* __restrict__ hidden_prev,
    float* __restrict__ hidden_out,
    int l)
{
    __shared__ float z[ZDIM];     // 24 KB
    __shared__ float gred[4];

    const int tid  = threadIdx.x;
    const int wave = tid >> 6;
    const int lane = tid & 63;
    const int h    = blockIdx.x;

    // stage z = [x ; hprev_l ; hidden_{l-1}]
    for (int i = tid; i < XDIM / 4; i += 256)
        reinterpret_cast<float4*>(z)[i] = reinterpret_cast<const float4*>(x)[i];
    reinterpret_cast<float4*>(z + XDIM)[tid] =
        reinterpret_cast<const float4*>(hprev + (size_t)l * HDIM)[tid];
    reinterpret_cast<float4*>(z + ZPAR)[tid] =
        reinterpret_cast<const float4*>(hidden_prev)[tid];
    __syncthreads();

    const size_t row = (size_t)l * 4096 + (size_t)wave * HDIM + h;
    const float4* __restrict__ W4 = reinterpret_cast<const float4*>(Wg + row * ZDIM);
    const float4* __restrict__ z4 = reinterpret_cast<const float4*>(z);

    // 1536 float4 per row; per lane 24, split as two streams of 12
    float accA = 0.0f, accB = 0.0f;
    #pragma unroll 4
    for (int p = 0; p < 12; ++p) {
        const int ia = p * 64 + lane;
        const int ib = ia + 768;
        float4 wa = W4[ia];
        float4 wb = W4[ib];
        float4 va = z4[ia];
        float4 vb = z4[ib];
        accA += wa.x * va.x + wa.y * va.y + wa.z * va.z + wa.w * va.w;
        accB += wb.x * vb.x + wb.y * vb.y + wb.z * vb.z + wb.w * vb.w;
    }
    float acc = accA + accB;
    #pragma unroll
    for (int off = 32; off > 0; off >>= 1)
        acc += __shfl_down(acc, off, 64);
    if (lane == 0)
        gred[wave] = acc + bg[row];
    __syncthreads();

    if (tid == 0) {
        const float ig = sigmoidf_(gred[0]);
        const float fg = sigmoidf_(gred[1]);
        const float og = sigmoidf_(gred[2]);
        const float sg = tanhf(gred[3]);
        const float ns = fg * old_state[(size_t)l * HDIM + h] + ig * sg;
        hidden_out[h] = og * tanhf(ns);
    }
}

// ---------------------------------------------------------------------------
// Layer-0 kernel: cols 0:5120 only (carry input is the zero vector).
// Same geometry; 20 float4/lane split as two streams of 10.
// ---------------------------------------------------------------------------
__global__ __launch_bounds__(256, 4) void layer0_kernel(
    const float* __restrict__ x,
    const float* __restrict__ hprev,
    const float* __restrict__ Wg,
    const float* __restrict__ bg,
    const float* __restrict__ old_state,
    float* __restrict__ hidden_out)
{
    __shared__ float z[ZPAR];     // 20 KB
    __shared__ float gred[4];

    const int tid  = threadIdx.x;
    const int wave = tid >> 6;
    const int lane = tid & 63;
    const int h    = blockIdx.x;

    for (int i = tid; i < XDIM / 4; i += 256)
        reinterpret_cast<float4*>(z)[i] = reinterpret_cast<const float4*>(x)[i];
    reinterpret_cast<float4*>(z + XDIM)[tid] =
        reinterpret_cast<const float4*>(hprev)[tid];
    __syncthreads();

    const size_t row = (size_t)wave * HDIM + h;
    const float4* __restrict__ W4 = reinterpret_cast<const float4*>(Wg + row * ZDIM);
    const float4* __restrict__ z4 = reinterpret_cast<const float4*>(z);

    // 1280 float4 per row; per lane 20, split as two streams of 10
    float accA = 0.0f, accB = 0.0f;
    #pragma unroll 5
    for (int p = 0; p < 10; ++p) {
        const int ia = p * 64 + lane;
        const int ib = ia + 640;
        float4 wa = W4[ia];
        float4 wb = W4[ib];
        float4 va = z4[ia];
        float4 vb = z4[ib];
        accA += wa.x * va.x + wa.y * va.y + wa.z * va.z + wa.w * va.w;
        accB += wb.x * vb.x + wb.y * vb.y + wb.z * vb.z + wb.w * vb.w;
    }
    float acc = accA + accB;
    #pragma unroll
    for (int off = 32; off > 0; off >>= 1)
        acc += __shfl_down(acc, off, 64);
    if (lane == 0)
        gred[wave] = acc + bg[row];
    __syncthreads();

    if (tid == 0) {
        const float ig = sigmoidf_(gred[0]);
        const float fg = sigmoidf_(gred[1]);
        const float og = sigmoidf_(gred[2]);
        const float sg = tanhf(gred[3]);
        const float ns = fg * old_state[h] + ig * sg;
        hidden_out[h] = og * tanhf(ns);
    }
}

// ---------------------------------------------------------------------------
// Heads: one block per output row (1536 blocks x 256).
// flat (32 KB) is L3-hot -> read directly from global, no LDS staging.
// ---------------------------------------------------------------------------
__global__ __launch_bounds__(256) void head_kernel(
    const float* __restrict__ Wy, const float* __restrict__ by,
    const float* __restrict__ We, const float* __restrict__ be,
    const float* __restrict__ flat,
    float* __restrict__ out)
{
    __shared__ float gred[4];

    const int tid  = threadIdx.x;
    const int wave = tid >> 6;
    const int lane = tid & 63;
    const int r    = blockIdx.x;

    const float* __restrict__ W;
    float b;
    if (r < VT) { W = Wy + (size_t)r * (LNUM * HDIM);        b = by[r]; }
    else        { W = We + (size_t)(r - VT) * (LNUM * HDIM); b = be[r - VT]; }

    const float4* __restrict__ W4 = reinterpret_cast<const float4*>(W);
    const float4* __restrict__ f4 = reinterpret_cast<const float4*>(flat);

    float acc = 0.0f;
    #pragma unroll
    for (int j = 0; j < 8; ++j) {               // 2048 float4 / 4 waves / 64 lanes
        const int idx = wave * 512 + j * 64 + lane;
        float4 w = W4[idx];
        float4 v = f4[idx];
        acc += w.x * v.x + w.y * v.y + w.z * v.z + w.w * v.w;
    }
    #pragma unroll
    for (int off = 32; off > 0; off >>= 1)
        acc += __shfl_down(acc, off, 64);
    if (lane == 0) gred[wave] = acc;
    __syncthreads();

    if (tid == 0)
        out[r] = gred[0] + gred[1] + gred[2] + gred[3] + b;
}

// ---------------------------------------------------------------------------
extern "C" void kernel_launch(void* const* d_in, const int* in_sizes, int n_in,
                              void* d_out, int out_size, void* d_ws, size_t ws_size,
                              hipStream_t stream)
{
    const float* x         = (const float*)d_in[0];
    const float* hprev     = (const float*)d_in[1];
    const float* Wg        = (const float*)d_in[2];
    const float* bg        = (const float*)d_in[3];
    const float* old_state = (const float*)d_in[4];
    const float* Wy        = (const float*)d_in[5];
    const float* by        = (const float*)d_in[6];
    const float* We        = (const float*)d_in[7];
    const float* be        = (const float*)d_in[8];
    float* out = (float*)d_out;

    float* hidden = (float*)d_ws;   // L*H floats

    // layer 0: prefix-only GEMV + cell
    layer0_kernel<<<1024, 256, 0, stream>>>(
        x, hprev, Wg, bg, old_state, hidden);

    // layers 1..7: full-width GEMV + cell (launch boundary = scan sync)
    for (int l = 1; l < LNUM; ++l) {
        layer_kernel<<<1024, 256, 0, stream>>>(
            x, hprev, Wg, bg, old_state,
            hidden + (size_t)(l - 1) * HDIM,
            hidden + (size_t)l * HDIM, l);
    }

    // heads
    head_kernel<<<VT + ET, 256, 0, stream>>>(Wy, by, We, be, hidden, out);
}

// Round 7
// 169.240 us; speedup vs baseline: 3.7458x; 1.0179x over previous
//
#include <hip/hip_runtime.h>
#include <hip/hip_bf16.h>
#include <cstddef>

// X=4096, H=1024, L=8, VT=512, ET=1024
// z = [input_x(4096) ; h_prev[l](1024) ; prev_layer(1024)] -> 6144 cols
// Wg: (L, 4H, 6144) row-major fp32. Gate order: i, f, o, s.
// Head: out[r] = sum_l Wh[r, l*H:(l+1)*H] . hidden[l] + bias  (Wh = Wy|We)

#define XDIM 4096
#define HDIM 1024
#define LNUM 8
#define ZDIM 6144
#define ZPAR 5120   // X + H (scan-independent prefix)
#define VT 512
#define ET 1024
#define NR (VT + ET)   // 1536 head rows

__device__ __forceinline__ float sigmoidf_(float v) {
    return 1.0f / (1.0f + expf(-v));
}
__device__ __forceinline__ float dot4_(float4 a, float4 b) {
    return a.x * b.x + a.y * b.y + a.z * b.z + a.w * b.w;
}

// ---------------------------------------------------------------------------
// Kernel P: prefix dots for ALL rows (cols 0:5120) + fused layer-0 LSTM cell.
// grid = 4096 blocks (8 layers x 512) x 256. Block b: l=b>>9, h0=(b&511)*2.
// Wave w computes rows rA=l*4096+w*1024+h0, rB=rA+1 (shared LDS z reads).
// ---------------------------------------------------------------------------
__global__ __launch_bounds__(256, 4) void prefix_kernel(
    const float* __restrict__ x,
    const float* __restrict__ hprev,
    const float* __restrict__ Wg,
    const float* __restrict__ bg,
    const float* __restrict__ old_state,
    float* __restrict__ partial,
    float* __restrict__ hidden)
{
    __shared__ float z[ZPAR];      // 20 KB
    __shared__ float g2[4][2];

    const int tid  = threadIdx.x;
    const int wave = tid >> 6;
    const int lane = tid & 63;
    const int l    = blockIdx.x >> 9;
    const int h0   = (blockIdx.x & 511) * 2;

    for (int i = tid; i < XDIM / 4; i += 256)
        reinterpret_cast<float4*>(z)[i] = reinterpret_cast<const float4*>(x)[i];
    reinterpret_cast<float4*>(z + XDIM)[tid] =
        reinterpret_cast<const float4*>(hprev + (size_t)l * HDIM)[tid];
    __syncthreads();

    const size_t rA = (size_t)l * 4096 + (size_t)wave * HDIM + h0;
    const size_t rB = rA + 1;
    const float4* __restrict__ WA = reinterpret_cast<const float4*>(Wg + rA * ZDIM);
    const float4* __restrict__ WB = reinterpret_cast<const float4*>(Wg + rB * ZDIM);
    const float4* __restrict__ z4 = reinterpret_cast<const float4*>(z);

    float accA = 0.0f, accB = 0.0f;
    #pragma unroll 4
    for (int p = 0; p < 20; ++p) {              // 1280 float4 / 64 lanes
        const int idx = p * 64 + lane;
        float4 wa = WA[idx];
        float4 wb = WB[idx];
        float4 v  = z4[idx];
        accA += dot4_(wa, v);
        accB += dot4_(wb, v);
    }
    #pragma unroll
    for (int off = 32; off > 0; off >>= 1) {
        accA += __shfl_down(accA, off, 64);
        accB += __shfl_down(accB, off, 64);
    }

    if (l > 0) {
        if (lane == 0) {
            partial[rA] = accA + bg[rA];
            partial[rB] = accB + bg[rB];
        }
    } else {
        if (lane == 0) {
            g2[wave][0] = accA + bg[rA];
            g2[wave][1] = accB + bg[rB];
        }
        __syncthreads();
        if (tid == 0) {
            #pragma unroll
            for (int k = 0; k < 2; ++k) {
                const float ig = sigmoidf_(g2[0][k]);
                const float fg = sigmoidf_(g2[1][k]);
                const float og = sigmoidf_(g2[2][k]);
                const float sg = tanhf(g2[3][k]);
                const float ns = fg * old_state[h0 + k] + ig * sg;
                hidden[h0 + k] = og * tanhf(ns);
            }
        }
    }
}

// ---------------------------------------------------------------------------
// Kernel C (per layer l=1..7): carry dot (cols 5120:6144) + cell math,
// PLUS head-chunk (l-1): headacc[r] += Wh[r,(l-1)H:lH] . hidden[l-1].
// grid = 1024 blocks x 256. Block h: wave q = gate q's carry dot.
// hidden[l-1] loaded per-lane direct from global (L2-hot, no LDS staging);
// wave w's carry fragment v_w doubles as its head slice (cols w*256..).
// Blocks 0..767 also handle head rows r0=2b, r1=2b+1 (2 extra loads/lane).
// l==1 WRITES headacc (ws is poisoned 0xAA, never accumulate into poison).
// ---------------------------------------------------------------------------
__global__ __launch_bounds__(256) void carry_kernel(
    const float* __restrict__ Wg,
    const float* __restrict__ partial,
    const float* __restrict__ old_state,
    const float* __restrict__ hidden_prev,  // hidden[l-1]
    float* __restrict__ hidden_out,         // hidden[l]
    const float* __restrict__ Wy,
    const float* __restrict__ We,
    float* __restrict__ headacc,            // NR floats
    int l)
{
    __shared__ float gred[4];
    __shared__ float hred[2][4];

    const int tid  = threadIdx.x;
    const int wave = tid >> 6;
    const int lane = tid & 63;
    const int h    = blockIdx.x;
    const bool do_head = (blockIdx.x < NR / 2);

    const size_t row = (size_t)l * 4096 + (size_t)wave * HDIM + h;
    const float4* __restrict__ W4 =
        reinterpret_cast<const float4*>(Wg + row * ZDIM + ZPAR);
    const float4* __restrict__ h4 =
        reinterpret_cast<const float4*>(hidden_prev);

    // issue all independent loads up front
    float4 w0 = W4[lane], w1 = W4[64 + lane], w2 = W4[128 + lane], w3 = W4[192 + lane];
    float4 v0 = h4[lane], v1 = h4[64 + lane], v2 = h4[128 + lane], v3 = h4[192 + lane];

    int r0 = 0, r1 = 0;
    float4 a0, a1;
    if (do_head) {
        r0 = 2 * blockIdx.x;
        r1 = r0 + 1;
        const float* Wr0 = (r0 < VT) ? (Wy + (size_t)r0 * (LNUM * HDIM))
                                     : (We + (size_t)(r0 - VT) * (LNUM * HDIM));
        const float* Wr1 = (r1 < VT) ? (Wy + (size_t)r1 * (LNUM * HDIM))
                                     : (We + (size_t)(r1 - VT) * (LNUM * HDIM));
        const int idx = (l - 1) * 256 + wave * 64 + lane;  // chunk l-1, wave slice
        a0 = reinterpret_cast<const float4*>(Wr0)[idx];
        a1 = reinterpret_cast<const float4*>(Wr1)[idx];
    }

    float acc = dot4_(w0, v0) + dot4_(w1, v1) + dot4_(w2, v2) + dot4_(w3, v3);
    #pragma unroll
    for (int off = 32; off > 0; off >>= 1)
        acc += __shfl_down(acc, off, 64);
    if (lane == 0)
        gred[wave] = acc + partial[row];        // partial already includes bg

    if (do_head) {
        // wave w's head slice of hidden = its carry fragment v_w
        float4 hv = (wave == 0) ? v0 : (wave == 1) ? v1 : (wave == 2) ? v2 : v3;
        float d0 = dot4_(a0, hv);
        float d1 = dot4_(a1, hv);
        #pragma unroll
        for (int off = 32; off > 0; off >>= 1) {
            d0 += __shfl_down(d0, off, 64);
            d1 += __shfl_down(d1, off, 64);
        }
        if (lane == 0) { hred[0][wave] = d0; hred[1][wave] = d1; }
    }
    __syncthreads();

    if (tid == 0) {
        const float ig = sigmoidf_(gred[0]);
        const float fg = sigmoidf_(gred[1]);
        const float og = sigmoidf_(gred[2]);
        const float sg = tanhf(gred[3]);
        const float ns = fg * old_state[(size_t)l * HDIM + h] + ig * sg;
        hidden_out[h] = og * tanhf(ns);
    }
    if (do_head) {
        if (tid == 64) {
            const float s = hred[0][0] + hred[0][1] + hred[0][2] + hred[0][3];
            headacc[r0] = ((l == 1) ? 0.0f : headacc[r0]) + s;
        }
        if (tid == 128) {
            const float s = hred[1][0] + hred[1][1] + hred[1][2] + hred[1][3];
            headacc[r1] = ((l == 1) ? 0.0f : headacc[r1]) + s;
        }
    }
}

// ---------------------------------------------------------------------------
// Kernel F: head finish. out[r] = headacc[r] + Wh[r, 7H:8H].hidden[7] + bias.
// grid = 1536 blocks x 256; wave w dots cols [7H + w*256, ...).
// ---------------------------------------------------------------------------
__global__ __launch_bounds__(256) void head_finish_kernel(
    const float* __restrict__ Wy, const float* __restrict__ by,
    const float* __restrict__ We, const float* __restrict__ be,
    const float* __restrict__ hidden,   // full flat (L*H)
    const float* __restrict__ headacc,
    float* __restrict__ out)
{
    __shared__ float gred[4];

    const int tid  = threadIdx.x;
    const int wave = tid >> 6;
    const int lane = tid & 63;
    const int r    = blockIdx.x;

    const float* W;
    float b;
    if (r < VT) { W = Wy + (size_t)r * (LNUM * HDIM);        b = by[r]; }
    else        { W = We + (size_t)(r - VT) * (LNUM * HDIM); b = be[r - VT]; }

    const int idx = 7 * 256 + wave * 64 + lane;   // chunk 7 float4 index
    float4 w = reinterpret_cast<const float4*>(W)[idx];
    float4 v = reinterpret_cast<const float4*>(hidden)[idx];

    float acc = dot4_(w, v);
    #pragma unroll
    for (int off = 32; off > 0; off >>= 1)
        acc += __shfl_down(acc, off, 64);
    if (lane == 0) gred[wave] = acc;
    __syncthreads();

    if (tid == 0)
        out[r] = headacc[r] + gred[0] + gred[1] + gred[2] + gred[3] + b;
}

// ---------------------------------------------------------------------------
extern "C" void kernel_launch(void* const* d_in, const int* in_sizes, int n_in,
                              void* d_out, int out_size, void* d_ws, size_t ws_size,
                              hipStream_t stream)
{
    const float* x         = (const float*)d_in[0];
    const float* hprev     = (const float*)d_in[1];
    const float* Wg        = (const float*)d_in[2];
    const float* bg        = (const float*)d_in[3];
    const float* old_state = (const float*)d_in[4];
    const float* Wy        = (const float*)d_in[5];
    const float* by        = (const float*)d_in[6];
    const float* We        = (const float*)d_in[7];
    const float* be        = (const float*)d_in[8];
    float* out = (float*)d_out;

    float* hidden  = (float*)d_ws;                 // L*H floats
    float* partial = hidden + LNUM * HDIM;         // L*4H floats
    float* headacc = partial + LNUM * 4 * HDIM;    // NR floats

    // 1) prefix dots for all layers + layer-0 cell
    prefix_kernel<<<4096, 256, 0, stream>>>(
        x, hprev, Wg, bg, old_state, partial, hidden);

    // 2) sequential carry chain (layers 1..7), head chunks 0..6 ride along
    for (int l = 1; l < LNUM; ++l) {
        carry_kernel<<<1024, 256, 0, stream>>>(
            Wg, partial, old_state,
            hidden + (size_t)(l - 1) * HDIM,
            hidden + (size_t)l * HDIM,
            Wy, We, headacc, l);
    }

    // 3) head finish: chunk 7 + bias
    head_finish_kernel<<<NR, 256, 0, stream>>>(
        Wy, by, We, be, hidden, headacc, out);
}